// Round 9
// baseline (355.286 us; speedup 1.0000x reference)
//
#include <hip/hip_runtime.h>
#include <stdint.h>

// MST on 128x256 grid, B=4, Boruvka with (weight, eid) total order.
// k_keys: weights, bit-exact seq accumulation (no FMA) — verified.
// k_dirs: per-node argmin direction (massively parallel, offloads round 0).
// k_mst4: 4 blocks (one per batch), all state in LDS.
//   Round 0: succ from dirs, 2-cycle break, pointer doubling (early exit),
//            renumber -> C0 <= 16384.
//   Round 1: u32 two-pass (bestW, then bestE) + per-edge winner (verified
//            pattern), renumber -> C1 <= 8192.
//   Rounds 2+: u64 single-pass LDS atomicMin of (w<<32)|e, PER-COMPONENT
//            hook/winner phase (no 2nd edge scan), no renumber (sparse root
//            ids < C1), terminate when selected == N-1.

#define HH 128
#define WW 256
#define NN (HH*WW)          // 32768 = 2^15
#define RE ((HH-1)*WW)      // 32512
#define EE (RE + HH*(WW-1)) // 65152
#define CH 64
#define EPAD 65536
#define TAG32 0x80000000u
#define TAG64 (1ull << 63)

typedef unsigned long long u64;
typedef unsigned int u32;
typedef unsigned short u16;
typedef unsigned char u8;

__device__ __forceinline__ void edge_uv(int e, int& u, int& v) {
    if (e < RE) { u = e; v = e + WW; }          // row edge (i,j)-(i+1,j)
    else {                                      // col edge (i,j)-(i,j+1)
        int ec = e - RE;
        int i = ec / (WW - 1);
        int j = ec - i * (WW - 1);
        u = i * WW + j; v = u + 1;
    }
}
__device__ __forceinline__ int edge_of(int n, int i, int j, int d) {
    return (d == 0) ? n - WW : (d == 1) ? n
         : (d == 2) ? RE + i * (WW - 1) + j - 1 : RE + i * (WW - 1) + j;
}
__device__ __forceinline__ int other_of(int n, int d) {
    return (d == 0) ? n - WW : (d == 1) ? n + WW : (d == 2) ? n - 1 : n + 1;
}

// weights for batches {b0, b0+2} per thread
__global__ __launch_bounds__(256) void k_keys(const float* __restrict__ g,
                                              u32* __restrict__ keyw) {
    int t = blockIdx.x * blockDim.x + threadIdx.x;   // 0..131071
    int e0 = t & (EPAD - 1);
    int b0 = t >> 16;                                // 0 or 1
    if (e0 >= EE) return;
    int u, v; edge_uv(e0, u, v);
    const float* gb0 = g + (size_t)b0 * CH * NN;
    const float* gb1 = gb0 + (size_t)2 * CH * NN;
    float a0 = 0.f, a1 = 0.f;
    #pragma unroll 8
    for (int c = 0; c < CH; ++c) {
        float x0 = gb0[(size_t)c * NN + u] - gb0[(size_t)c * NN + v];
        float x1 = gb1[(size_t)c * NN + u] - gb1[(size_t)c * NN + v];
        a0 = __fadd_rn(a0, __fmul_rn(x0, x0));       // forbid fma contraction
        a1 = __fadd_rn(a1, __fmul_rn(x1, x1));
    }
    keyw[(b0 << 16) | e0] = __float_as_uint(sqrtf(a0));
    keyw[((b0 + 2) << 16) | e0] = __float_as_uint(sqrtf(a1));
}

// per-(batch,node) argmin incident edge -> 2-bit dir as u8
__global__ __launch_bounds__(256) void k_dirs(const u32* __restrict__ keyw,
                                              u8* __restrict__ gdir) {
    int t = blockIdx.x * blockDim.x + threadIdx.x;   // 0..131071
    int b = t >> 15, n = t & (NN - 1);
    const u32* kb = keyw + (b << 16);
    int i = n >> 8, j = n & 255;
    u64 bk = ~0ull; int bd = 0;
    if (i > 0)      { int e = n - WW;               u64 kk = ((u64)kb[e] << 32) | (u32)e; if (kk < bk) { bk = kk; bd = 0; } }
    if (i < HH - 1) { int e = n;                    u64 kk = ((u64)kb[e] << 32) | (u32)e; if (kk < bk) { bk = kk; bd = 1; } }
    if (j > 0)      { int e = RE + i * (WW-1) + j-1; u64 kk = ((u64)kb[e] << 32) | (u32)e; if (kk < bk) { bk = kk; bd = 2; } }
    if (j < WW - 1) { int e = RE + i * (WW-1) + j;   u64 kk = ((u64)kb[e] << 32) | (u32)e; if (kk < bk) { bk = kk; bd = 3; } }
    gdir[t] = (u8)bd;
}

__global__ __launch_bounds__(1024) void k_mst4(const u32* __restrict__ keyw,
                                               const u8* __restrict__ gdir,
                                               int* __restrict__ out) {
    __shared__ u16 lab[NN];          // 64 KB node -> comp id
    __shared__ u64 Wbuf[8192];       // 64 KB (views: W32 u32[16384], W16 u16[32768])
    __shared__ u32 selw[EPAD / 32];  // 8 KB edge bitmask
    __shared__ int wsum[32];
    __shared__ int cntc, nsel;
    __shared__ int dflag[2];

    u32* W32 = (u32*)Wbuf;
    u16* W16 = (u16*)Wbuf;

    const int b = (int)blockIdx.x;
    const int tid = (int)threadIdx.x;
    const int lane = tid & 63;
    const u32* kb = keyw + (b << 16);
    const u8* gd = gdir + (b << 15);

    for (int k = tid; k < EPAD / 32; k += 1024) selw[k] = 0u;
    if (tid == 0) { cntc = 0; nsel = 0; dflag[0] = 0; dflag[1] = 0; }
    __syncthreads();

    // ======== round 0: succ from dirs (2-cycle broken), mark sel ==========
    for (int n = tid; n < NN; n += 1024) {
        int d = gd[n];
        int i = n >> 8, j = n & 255;
        int e = edge_of(n, i, j, d);
        int o = other_of(n, d);
        atomicOr(&selw[e >> 5], 1u << (e & 31));
        int d2 = gd[o];
        int e2 = edge_of(o, o >> 8, o & 255, d2);
        W16[n] = (u16)((e2 == e && n < o) ? n : o);
    }
    __syncthreads();
    // pointer doubling with early exit (ping-pong flags)
    for (int it = 0; it < 15; ++it) {
        if (tid == 0) dflag[(it + 1) & 1] = 0;
        int chg = 0;
        #pragma unroll
        for (int n0 = 0; n0 < 4; ++n0) {
            u16 x[8], y[8];
            #pragma unroll
            for (int i = 0; i < 8; ++i) x[i] = W16[tid + ((n0 * 8 + i) << 10)];
            #pragma unroll
            for (int i = 0; i < 8; ++i) y[i] = W16[x[i]];
            #pragma unroll
            for (int i = 0; i < 8; ++i)
                if (x[i] != y[i]) { W16[tid + ((n0 * 8 + i) << 10)] = y[i]; chg = 1; }
        }
        if (chg) dflag[it & 1] = 1;
        __syncthreads();
        if (!dflag[it & 1]) break;
    }
    for (int n = tid; n < NN; n += 1024) lab[n] = W16[n];   // node-space roots
    __syncthreads();
    for (int n = tid; n < NN; n += 1024) {                  // renumber roots
        bool isr = (lab[n] == (u16)n);
        u64 bal = __ballot(isr);
        u32 base2 = 0;
        if (lane == 0 && bal) base2 = (u32)atomicAdd(&cntc, (int)__popcll(bal));
        base2 = (u32)__shfl((int)base2, 0, 64);
        if (isr) W16[n] = (u16)(base2 + (u32)__popcll(bal & ((1ull << lane) - 1)));
    }
    __syncthreads();
    for (int n = tid; n < NN; n += 1024) lab[n] = W16[lab[n]];
    __syncthreads();
    int C = cntc;                    // C0 <= 16384
    int tot = NN - C;

    // thread's edge k-bit <-> e = (k<<10)+tid ; k=63 invalid for tid>=640
    u64 dead = (tid >= (EE - 63 * 1024)) ? (1ull << 63) : 0ull;

    // ======== round 1: u32 two-pass, renumber -> C1 <= 8192 ===============
    if (tot < NN - 1) {
        for (int c = tid; c < C; c += 1024) W32[c] = ~0u;
        __syncthreads();
        u64 act = 0;
        for (int c8 = 0; c8 < 8; ++c8) {                    // pass A: bestW
            u32 alive = (u32)((~dead) >> (c8 * 8)) & 0xFFu;
            if (!alive) continue;
            u32 cu[8], cv[8], kw[8];
            #pragma unroll
            for (int i = 0; i < 8; ++i) if (alive & (1u << i)) {
                int e = ((c8 * 8 + i) << 10) + tid; int u, v; edge_uv(e, u, v);
                cu[i] = lab[u]; cv[i] = lab[v]; kw[i] = kb[e];
            }
            #pragma unroll
            for (int i = 0; i < 8; ++i) if (alive & (1u << i)) {
                int k = c8 * 8 + i;
                if (cu[i] == cv[i]) dead |= 1ull << k;
                else {
                    act |= 1ull << k;
                    atomicMin(&W32[cu[i]], kw[i]);
                    atomicMin(&W32[cv[i]], kw[i]);
                }
            }
        }
        __syncthreads();
        u64 mu = 0, mv = 0;
        for (int c8 = 0; c8 < 8; ++c8) {                    // pass B: match
            u32 am = (u32)(act >> (c8 * 8)) & 0xFFu;
            if (!am) continue;
            u32 cu[8], cv[8], kw[8];
            #pragma unroll
            for (int i = 0; i < 8; ++i) if (am & (1u << i)) {
                int e = ((c8 * 8 + i) << 10) + tid; int u, v; edge_uv(e, u, v);
                cu[i] = lab[u]; cv[i] = lab[v]; kw[i] = kb[e];
            }
            #pragma unroll
            for (int i = 0; i < 8; ++i) if (am & (1u << i)) {
                int k = c8 * 8 + i;
                if (W32[cu[i]] == kw[i]) mu |= 1ull << k;
                if (W32[cv[i]] == kw[i]) mv |= 1ull << k;
            }
        }
        __syncthreads();
        for (int c = tid; c < C; c += 1024) W32[c] = ~0u;
        __syncthreads();
        u64 mm0 = mu | mv;
        for (int c8 = 0; c8 < 8; ++c8) {                    // pass C: bestE
            u32 am = (u32)(mm0 >> (c8 * 8)) & 0xFFu;
            if (!am) continue;
            u32 cu[8], cv[8];
            #pragma unroll
            for (int i = 0; i < 8; ++i) if (am & (1u << i)) {
                int e = ((c8 * 8 + i) << 10) + tid; int u, v; edge_uv(e, u, v);
                cu[i] = lab[u]; cv[i] = lab[v];
            }
            #pragma unroll
            for (int i = 0; i < 8; ++i) if (am & (1u << i)) {
                int k = c8 * 8 + i; int e = (k << 10) + tid;
                if ((mu >> k) & 1) atomicMin(&W32[cu[i]], (u32)e);
                if ((mv >> k) & 1) atomicMin(&W32[cv[i]], (u32)e);
            }
        }
        __syncthreads();
        for (int c8 = 0; c8 < 8; ++c8) {                    // pass D: winners
            u32 am = (u32)(mm0 >> (c8 * 8)) & 0xFFu;
            if (!am) continue;
            u32 cu[8], cv[8], eu2[8], ev2[8];
            #pragma unroll
            for (int i = 0; i < 8; ++i) if (am & (1u << i)) {
                int e = ((c8 * 8 + i) << 10) + tid; int u, v; edge_uv(e, u, v);
                cu[i] = lab[u]; cv[i] = lab[v];
                eu2[i] = W32[cu[i]]; ev2[i] = W32[cv[i]];
            }
            #pragma unroll
            for (int i = 0; i < 8; ++i) if (am & (1u << i)) {
                int k = c8 * 8 + i; int e = (k << 10) + tid;
                bool wU = ((mu >> k) & 1) && (eu2[i] == (u32)e);  // TAG kills stale
                bool wV = ((mv >> k) & 1) && (ev2[i] == (u32)e);
                if (wU | wV) {
                    atomicOr(&selw[e >> 5], 1u << (e & 31));
                    u32 a = cu[i], d2 = cv[i];
                    if (wU && wV) { u32 mn = a < d2 ? a : d2, mx = a ^ d2 ^ mn;
                                    W32[mx] = TAG32 | mn; W32[mn] = TAG32 | mn; }
                    else if (wU)  W32[a]  = TAG32 | d2;
                    else          W32[d2] = TAG32 | a;
                }
            }
        }
        if (tid == 0) cntc = 0;
        __syncthreads();
        for (int c = tid; c < C; c += 1024) {               // compress
            u32 x = (u32)c, nx = W32[x] & 0x3FFFu;
            while (nx != x) { x = nx; nx = W32[x] & 0x3FFFu; }
            W32[c] = TAG32 | x;
        }
        __syncthreads();
        for (int c = tid; c < C; c += 1024) {               // renumber roots
            bool isr = ((W32[c] & 0x3FFFu) == (u32)c);
            u64 bal = __ballot(isr);
            u32 base2 = 0;
            if (lane == 0 && bal) base2 = (u32)atomicAdd(&cntc, (int)__popcll(bal));
            base2 = (u32)__shfl((int)base2, 0, 64);
            if (isr) W32[c] = TAG32 | (u32)c |
                              ((base2 + (u32)__popcll(bal & ((1ull << lane) - 1))) << 16);
        }
        __syncthreads();
        for (int n = tid; n < NN; n += 1024) {              // relabel
            u32 rr = W32[lab[n]] & 0x3FFFu;
            lab[n] = (u16)((W32[rr] >> 16) & 0x1FFFu);
        }
        __syncthreads();
        C = cntc;                                           // C1 <= 8192
        tot = NN - C;
    }

    // ======== rounds 2..14: u64 single-pass + per-comp hook ===============
    for (int r = 2; r < 15 && tot < NN - 1; ++r) {
        for (int c = tid; c < C; c += 1024) Wbuf[c] = ~0ull;
        if (tid == 0) nsel = 0;
        __syncthreads();
        // phase A: per-edge scatter-min (the only per-edge pass)
        for (int c8 = 0; c8 < 8; ++c8) {
            u32 alive = (u32)((~dead) >> (c8 * 8)) & 0xFFu;
            if (!alive) continue;
            u32 cu[8], cv[8], kw[8];
            #pragma unroll
            for (int i = 0; i < 8; ++i) if (alive & (1u << i)) {
                int e = ((c8 * 8 + i) << 10) + tid; int u, v; edge_uv(e, u, v);
                cu[i] = lab[u]; cv[i] = lab[v]; kw[i] = kb[e];
            }
            #pragma unroll
            for (int i = 0; i < 8; ++i) if (alive & (1u << i)) {
                int k = c8 * 8 + i; int e = (k << 10) + tid;
                if (cu[i] == cv[i]) dead |= 1ull << k;
                else {
                    u64 key = ((u64)kw[i] << 32) | (u32)e;
                    atomicMin(&Wbuf[cu[i]], key);
                    atomicMin(&Wbuf[cv[i]], key);
                }
            }
        }
        __syncthreads();
        // phase H: per-comp read (own argmin + mutual check)
        u32 hval = 0;                     // bit i: valid, bit i+8: count-me
        int he[8]; u16 ho[8];
        #pragma unroll
        for (int i = 0; i < 8; ++i) {
            int c = tid + (i << 10);
            if (c < C) {
                u64 wv = Wbuf[c];
                if (wv != ~0ull) {
                    int e = (int)(u32)wv; int u, v; edge_uv(e, u, v);
                    u32 lu = lab[u], lv = lab[v];
                    u32 o = (lu == (u32)c) ? lv : lu;
                    bool mut = (Wbuf[o] == wv);
                    he[i] = e;
                    ho[i] = (u16)(mut ? ((u32)c < o ? (u32)c : o) : o);
                    hval |= 1u << i;
                    if (!mut || (u32)c < o) hval |= 1u << (i + 8);
                }
            }
        }
        __syncthreads();
        // phase W: per-comp hook write + sel + merge count
        int myns = 0;
        #pragma unroll
        for (int i = 0; i < 8; ++i) {
            int c = tid + (i << 10);
            if (c < C) {
                if (hval & (1u << i)) {
                    if (hval & (1u << (i + 8))) {
                        int e = he[i];
                        atomicOr(&selw[e >> 5], 1u << (e & 31));
                        ++myns;
                    }
                    Wbuf[c] = TAG64 | (u32)ho[i];
                } else {
                    Wbuf[c] = TAG64 | (u32)c;
                }
            }
        }
        if (myns) atomicAdd(&nsel, myns);
        __syncthreads();
        // compress to roots
        #pragma unroll
        for (int i = 0; i < 8; ++i) {
            int c = tid + (i << 10);
            if (c < C) {
                u32 x = (u32)c, nx = (u32)Wbuf[x] & 0x1FFFu;
                while (nx != x) { x = nx; nx = (u32)Wbuf[x] & 0x1FFFu; }
                Wbuf[c] = TAG64 | x;
            }
        }
        __syncthreads();
        int ns = nsel;                    // read before next-round reset
        // relabel (2-dep, staged)
        #pragma unroll
        for (int n0 = 0; n0 < 4; ++n0) {
            u16 l8[8];
            #pragma unroll
            for (int i = 0; i < 8; ++i) l8[i] = lab[tid + ((n0 * 8 + i) << 10)];
            #pragma unroll
            for (int i = 0; i < 8; ++i) l8[i] = (u16)((u32)Wbuf[l8[i]] & 0x1FFFu);
            #pragma unroll
            for (int i = 0; i < 8; ++i) lab[tid + ((n0 * 8 + i) << 10)] = l8[i];
        }
        __syncthreads();
        tot += ns;
    }

    // ---- in-block stable compaction from LDS bitmask (thread owns 64 eids)
    u32 w0 = selw[tid * 2], w1 = selw[tid * 2 + 1];
    int cnt = __popc(w0) + __popc(w1);
    int wid = tid >> 6;
    int inc = cnt;
    #pragma unroll
    for (int d = 1; d < 64; d <<= 1) {
        int t2 = __shfl_up(inc, d, 64);
        if (lane >= d) inc += t2;
    }
    if (lane == 63) wsum[wid] = inc;
    __syncthreads();
    if (tid < 16) {
        int vv = wsum[tid];
        int inc2 = vv;
        #pragma unroll
        for (int d = 1; d < 16; d <<= 1) {
            int t2 = __shfl_up(inc2, d, 16);
            if (tid >= d) inc2 += t2;
        }
        wsum[tid] = inc2 - vv;                      // exclusive wave base
    }
    __syncthreads();
    int pos = wsum[wid] + inc - cnt;
    int* ob = out + (size_t)b * (NN - 1) * 2;
    u64 bits = ((u64)w1 << 32) | (u64)w0;
    while (bits) {
        int bi = __ffsll((long long)bits) - 1;
        bits &= bits - 1;
        int e = (tid << 6) + bi;
        int u, v; edge_uv(e, u, v);
        ob[(size_t)pos * 2] = u;
        ob[(size_t)pos * 2 + 1] = v;
        ++pos;
    }
}

extern "C" void kernel_launch(void* const* d_in, const int* in_sizes, int n_in,
                              void* d_out, int out_size, void* d_ws, size_t ws_size,
                              hipStream_t stream) {
    const float* g = (const float*)d_in[0];
    int* out = (int*)d_out;
    char* ws = (char*)d_ws;

    u32* keyw = (u32*)ws;                            // B*EPAD*4 = 1 MB
    u8*  gdir = (u8*)(ws + (size_t)4 * EPAD * 4);    // B*N = 128 KB

    k_keys<<<512, 256, 0, stream>>>(g, keyw);
    k_dirs<<<512, 256, 0, stream>>>(keyw, gdir);
    k_mst4<<<4, 1024, 0, stream>>>(keyw, gdir, out);
}

// Round 10
// 165.944 us; speedup vs baseline: 2.1410x; 2.1410x over previous
//
#include <hip/hip_runtime.h>
#include <stdint.h>

// MST on 128x256 grid, B=4, Boruvka with (weight, eid) total order.
// Full-GPU multi-kernel, ONE kernel per round:
//   kernel r consumes best[r-1] (complete via kernel boundary): node-role
//   marks sel bits + resets buf[r+1]; edge-role chases the round-(r-1)
//   argmin forest on the fly (mutual-pair stop, min-id root), path-
//   compresses lab, and atomicMins (key<<32|e) into buf[r].
//   3-buffer rotation => no in-round reset/read races.
// k_keys: bit-exact weights (sequential __fadd_rn(__fmul_rn), no FMA).
// k_dirs: per-node argmin into buf0 (= reference round 0), init state.
// k_compact: verified in-block ballot-scan compaction from sel bitmask.

#define HH 128
#define WW 256
#define NN (HH*WW)          // 32768 = 2^15
#define RE ((HH-1)*WW)      // 32512
#define EE (RE + HH*(WW-1)) // 65152
#define CH 64
#define EPAD 65536
#define NB4 (4*NN)          // 131072

typedef unsigned long long u64;
typedef unsigned int u32;
typedef unsigned short u16;

__device__ __forceinline__ void edge_uv(int e, int& u, int& v) {
    if (e < RE) { u = e; v = e + WW; }          // row edge (i,j)-(i+1,j)
    else {                                      // col edge (i,j)-(i,j+1)
        int ec = e - RE;
        int i = ec / (WW - 1);
        int j = ec - i * (WW - 1);
        u = i * WW + j; v = u + 1;
    }
}

// ---- weights for batches {b0, b0+2} per thread (bit-exact, verified)
__global__ __launch_bounds__(256) void k_keys(const float* __restrict__ g,
                                              u32* __restrict__ keyw) {
    int t = blockIdx.x * blockDim.x + threadIdx.x;   // 0..131071
    int e0 = t & (EPAD - 1);
    int b0 = t >> 16;                                // 0 or 1
    if (e0 >= EE) return;
    int u, v; edge_uv(e0, u, v);
    const float* gb0 = g + (size_t)b0 * CH * NN;
    const float* gb1 = gb0 + (size_t)2 * CH * NN;
    float a0 = 0.f, a1 = 0.f;
    #pragma unroll 8
    for (int c = 0; c < CH; ++c) {
        float x0 = gb0[(size_t)c * NN + u] - gb0[(size_t)c * NN + v];
        float x1 = gb1[(size_t)c * NN + u] - gb1[(size_t)c * NN + v];
        a0 = __fadd_rn(a0, __fmul_rn(x0, x0));       // forbid fma contraction
        a1 = __fadd_rn(a1, __fmul_rn(x1, x1));
    }
    keyw[(b0 << 16) | e0] = __float_as_uint(sqrtf(a0));
    keyw[((b0 + 2) << 16) | e0] = __float_as_uint(sqrtf(a1));
}

// ---- per-(batch,node) argmin edge -> buf0 (= reference round 0) + init all
__global__ __launch_bounds__(256) void k_dirs(const u32* __restrict__ keyw,
                                              u64* __restrict__ buf0,
                                              u64* __restrict__ buf1,
                                              u16* __restrict__ lab,
                                              u32* __restrict__ selw,
                                              int* __restrict__ flags) {
    int t = blockIdx.x * blockDim.x + threadIdx.x;   // 0..131071
    int b = t >> 15, n = t & (NN - 1);
    const u32* kb = keyw + (b << 16);
    int i = n >> 8, j = n & 255;
    u64 bk = ~0ull;
    if (i > 0)      { int e = n - WW;                u64 kk = ((u64)kb[e] << 32) | (u32)e; bk = kk < bk ? kk : bk; }
    if (i < HH - 1) { int e = n;                     u64 kk = ((u64)kb[e] << 32) | (u32)e; bk = kk < bk ? kk : bk; }
    if (j > 0)      { int e = RE + i * (WW-1) + j-1; u64 kk = ((u64)kb[e] << 32) | (u32)e; bk = kk < bk ? kk : bk; }
    if (j < WW - 1) { int e = RE + i * (WW-1) + j;   u64 kk = ((u64)kb[e] << 32) | (u32)e; bk = kk < bk ? kk : bk; }
    buf0[t] = bk;                    // every node has >=2 edges: bk != ~0
    buf1[t] = ~0ull;
    lab[t] = (u16)n;                 // identity labels
    if (t < 4 * (EPAD / 32)) selw[t] = 0u;
    if (t < 32) flags[t] = (t == 0) ? 1 : 0;
}

// ---- chase x through the prev-round argmin forest to its component root.
// Concurrent lab updates only jump the walk forward within the same
// component; mutual-pair check (same edge chosen by both sides) terminates
// with root = min(pair) — the verified 2-cycle rule.
__device__ __forceinline__ u32 chase_root(u32 x, const u64* __restrict__ bp,
                                          const u16* __restrict__ labB) {
    for (;;) {
        u64 k = bp[x];
        if (k == ~0ull) return x;                    // x merged nothing: root
        int e = (int)(u32)k;
        int uu, vv; edge_uv(e, uu, vv);
        u32 lu = labB[uu], lv = labB[vv];
        u32 o = (lu == x) ? lv : lu;
        if (o == x) return x;                        // fully-relabeled internal
        u64 k2 = bp[o];
        if ((u32)k2 == (u32)e) return (x < o) ? x : o;   // mutual pair
        x = o;
    }
}

// ---- one Boruvka round, full GPU. 1024 blocks x 256 threads.
__global__ __launch_bounds__(256) void k_round(const u32* __restrict__ keyw,
                                               u16* __restrict__ lab,
                                               const u64* __restrict__ bufp,
                                               u64* __restrict__ bufc,
                                               u64* __restrict__ bufn,
                                               u32* __restrict__ selw,
                                               int* __restrict__ flags, int r) {
    if (flags[r - 1] == 0) return;                   // converged: nothing left
    int t = blockIdx.x * blockDim.x + threadIdx.x;   // 0..262143
    // node-role: mark prev round's winner edges; reset buf for round r+1
    if (t < NB4) {
        u64 bp = bufp[t];
        if (bp != ~0ull) {
            int e = (int)(u32)bp;
            int b = t >> 15;
            atomicOr(&selw[(b << 11) + (e >> 5)], 1u << (e & 31));
        }
        bufn[t] = ~0ull;
    }
    // edge-role: chase both endpoints to round-r roots, compress, scatter-min
    int b = t >> 16, e = t & (EPAD - 1);
    if (e >= EE) return;
    u16* labB = lab + (b << 15);
    const u64* bp = bufp + (b << 15);
    int uu, vv; edge_uv(e, uu, vv);
    u32 ru = chase_root(labB[uu], bp, labB);
    u32 rv = chase_root(labB[vv], bp, labB);
    labB[uu] = (u16)ru; labB[vv] = (u16)rv;          // benign same-value races
    if (ru == rv) return;                            // dead edge
    u64 key = ((u64)keyw[(b << 16) | e] << 32) | (u32)e;
    u64* bc = bufc + (b << 15);
    atomicMin(bc + ru, key);
    atomicMin(bc + rv, key);
    flags[r] = 1;                                    // benign race: same value
}

// ---- compaction: 4 blocks (one per batch), verified ballot-scan
__global__ __launch_bounds__(1024) void k_compact(const u32* __restrict__ selw,
                                                  int* __restrict__ out) {
    __shared__ int wsum[32];
    const int b = (int)blockIdx.x;
    const int tid = (int)threadIdx.x;
    u32 w0 = selw[(b << 11) + tid * 2], w1 = selw[(b << 11) + tid * 2 + 1];
    int cnt = __popc(w0) + __popc(w1);
    int lane = tid & 63, wid = tid >> 6;
    int inc = cnt;
    #pragma unroll
    for (int d = 1; d < 64; d <<= 1) {
        int t2 = __shfl_up(inc, d, 64);
        if (lane >= d) inc += t2;
    }
    if (lane == 63) wsum[wid] = inc;
    __syncthreads();
    if (tid < 16) {
        int vv = wsum[tid];
        int inc2 = vv;
        #pragma unroll
        for (int d = 1; d < 16; d <<= 1) {
            int t2 = __shfl_up(inc2, d, 16);
            if (tid >= d) inc2 += t2;
        }
        wsum[tid] = inc2 - vv;                       // exclusive wave base
    }
    __syncthreads();
    int pos = wsum[wid] + inc - cnt;
    int* ob = out + (size_t)b * (NN - 1) * 2;
    u64 bits = ((u64)w1 << 32) | (u64)w0;
    while (bits) {
        int bi = __ffsll((long long)bits) - 1;
        bits &= bits - 1;
        int e = (tid << 6) + bi;
        int u, v; edge_uv(e, u, v);
        ob[(size_t)pos * 2] = u;
        ob[(size_t)pos * 2 + 1] = v;
        ++pos;
    }
}

extern "C" void kernel_launch(void* const* d_in, const int* in_sizes, int n_in,
                              void* d_out, int out_size, void* d_ws, size_t ws_size,
                              hipStream_t stream) {
    const float* g = (const float*)d_in[0];
    int* out = (int*)d_out;
    char* ws = (char*)d_ws;

    // workspace (~4.3 MB)
    u32* keyw = (u32*)ws;                            // B*EPAD*4 = 1 MB
    u64* buf0 = (u64*)(ws + (1u << 20));             // 1 MB
    u64* buf1 = (u64*)(ws + (2u << 20));             // 1 MB
    u64* buf2 = (u64*)(ws + (3u << 20));             // 1 MB
    u16* lab  = (u16*)(ws + (4u << 20));             // 256 KB
    u32* selw = (u32*)(ws + (4u << 20) + (NB4 * 2)); // 32 KB
    int* flags = (int*)(ws + (4u << 20) + (NB4 * 2) + 4 * (EPAD / 32) * 4);

    u64* bufs[3] = {buf0, buf1, buf2};

    k_keys<<<512, 256, 0, stream>>>(g, keyw);
    k_dirs<<<512, 256, 0, stream>>>(keyw, buf0, buf1, lab, selw, flags);
    for (int r = 1; r <= 16; ++r) {
        u64* bp = bufs[(r - 1) % 3];
        u64* bc = bufs[r % 3];
        u64* bn = bufs[(r + 1) % 3];
        k_round<<<1024, 256, 0, stream>>>(keyw, lab, bp, bc, bn, selw, flags, r);
    }
    k_compact<<<4, 1024, 0, stream>>>(selw, out);
}